// Round 5
// baseline (2948.479 us; speedup 1.0000x reference)
//
#include <hip/hip_runtime.h>
#include <hip/hip_bf16.h>

// ChebNet: N=100000, E=1600000, IN=HID=128, OUT=40, K=3, 5 hidden layers.
//  - CSR by dst built per-launch (3-phase multi-block scan).
//  - Per layer: B1 = -spmm(X); B2 = -2*spmm(B1) - X; H = relu([X|B1|B2] @ W + b)
//  - GEMM v3: LDS-free bf16x3 MFMA. W pre-transposed+converted once per launch
//    into [n][k] hi/lo bf16; A fragments loaded fp32 from global, converted
//    in-register. No barriers, no bank conflicts.

#define NN 100000
#define EE 1600000
#define FF 128

typedef __attribute__((ext_vector_type(8))) short short8_t;
typedef __attribute__((ext_vector_type(4))) float floatx4;
typedef __attribute__((ext_vector_type(4))) float accfrag;

// ---------------- CSR build ----------------

__global__ void hist_kernel(const int* __restrict__ dst, int* __restrict__ cnt, int e) {
    int i = blockIdx.x * blockDim.x + threadIdx.x;
    if (i < e) atomicAdd(&cnt[dst[i]], 1);
}

__global__ __launch_bounds__(256) void scan_p1_kernel(const int* __restrict__ cnt,
                                                      int* __restrict__ bsum, int n) {
    __shared__ int red[8];
    int i = blockIdx.x * 256 + threadIdx.x;
    int v = (i < n) ? cnt[i] : 0;
    for (int off = 32; off > 0; off >>= 1) v += __shfl_down(v, off, 64);
    int wv = threadIdx.x >> 6;
    if ((threadIdx.x & 63) == 0) red[wv] = v;
    __syncthreads();
    if (threadIdx.x == 0) bsum[blockIdx.x] = red[0] + red[1] + red[2] + red[3];
}

__global__ __launch_bounds__(1024) void scan_p2_kernel(int* __restrict__ bsum, int nb) {
    __shared__ int s[1024];
    int tid = threadIdx.x;
    int v = (tid < nb) ? bsum[tid] : 0;
    s[tid] = v;
    __syncthreads();
    for (int off = 1; off < 1024; off <<= 1) {
        int u = (tid >= off) ? s[tid - off] : 0;
        __syncthreads();
        s[tid] += u;
        __syncthreads();
    }
    if (tid < nb) bsum[tid] = s[tid] - v;
}

__global__ __launch_bounds__(256) void scan_p3_kernel(const int* __restrict__ cnt,
                                                      const int* __restrict__ bsum,
                                                      int* __restrict__ row_ptr, int n) {
    __shared__ int s[256];
    int tid = threadIdx.x;
    int i = blockIdx.x * 256 + tid;
    int v = (i < n) ? cnt[i] : 0;
    s[tid] = v;
    __syncthreads();
    for (int off = 1; off < 256; off <<= 1) {
        int u = (tid >= off) ? s[tid - off] : 0;
        __syncthreads();
        s[tid] += u;
        __syncthreads();
    }
    if (i < n) {
        int excl = bsum[blockIdx.x] + s[tid] - v;
        row_ptr[i] = excl;
        if (i == n - 1) row_ptr[n] = excl + v;
    }
}

__global__ void dinv_kernel(const int* __restrict__ row_ptr, float* __restrict__ dinv, int n) {
    int i = blockIdx.x * blockDim.x + threadIdx.x;
    if (i >= n) return;
    int d = row_ptr[i + 1] - row_ptr[i];
    if (d < 1) d = 1;
    dinv[i] = 1.0f / sqrtf((float)d);
}

__global__ void scatter_kernel(const int* __restrict__ src, const int* __restrict__ dst,
                               const int* __restrict__ row_ptr, int* __restrict__ fill,
                               int* __restrict__ col_src, int e) {
    int i = blockIdx.x * blockDim.x + threadIdx.x;
    if (i >= e) return;
    int d = dst[i];
    int pos = row_ptr[d] + atomicAdd(&fill[d], 1);
    col_src[pos] = src[i];
}

// ---------------- fp32 -> bf16 hi/lo split ----------------

__device__ inline void f2bf_hilo(float x, short* hi, short* lo) {
    union { float f; unsigned u; } a; a.f = x;
    unsigned uh = a.u + 0x7FFFu + ((a.u >> 16) & 1u);
    unsigned short h = (unsigned short)(uh >> 16);
    union { unsigned u; float f; } hf; hf.u = ((unsigned)h) << 16;
    float r = x - hf.f;
    union { float f; unsigned u; } b; b.f = r;
    unsigned ul = b.u + 0x7FFFu + ((b.u >> 16) & 1u);
    *hi = (short)h; *lo = (short)(ul >> 16);
}

__device__ inline void cvt8(floatx4 a, floatx4 b, short8_t* hi, short8_t* lo) {
    short h[8], l[8];
    f2bf_hilo(a.x, &h[0], &l[0]);
    f2bf_hilo(a.y, &h[1], &l[1]);
    f2bf_hilo(a.z, &h[2], &l[2]);
    f2bf_hilo(a.w, &h[3], &l[3]);
    f2bf_hilo(b.x, &h[4], &l[4]);
    f2bf_hilo(b.y, &h[5], &l[5]);
    f2bf_hilo(b.z, &h[6], &l[6]);
    f2bf_hilo(b.w, &h[7], &l[7]);
    *hi = (short8_t){ h[0], h[1], h[2], h[3], h[4], h[5], h[6], h[7] };
    *lo = (short8_t){ l[0], l[1], l[2], l[3], l[4], l[5], l[6], l[7] };
}

// ---------------- W precompute: [layer][ncol(128)][k(384)] hi/lo bf16 ----------------

__global__ __launch_bounds__(256) void wprep_kernel(
    const float* __restrict__ W0, const float* __restrict__ Wh, const float* __restrict__ Wl,
    short* __restrict__ Whi_t, short* __restrict__ Wlo_t)
{
    int idx = blockIdx.x * 256 + threadIdx.x;
    const int PER = 128 * 384;
    if (idx >= 7 * PER) return;
    int layer = idx / PER;
    int rem = idx - layer * PER;
    int ncol = rem / 384;
    int k = rem - ncol * 384;
    const float* W; int outc;
    if (layer == 0)      { W = W0; outc = 128; }
    else if (layer < 6)  { W = Wh + (size_t)(layer - 1) * 384 * 128; outc = 128; }
    else                 { W = Wl; outc = 40; }
    float v = (ncol < outc) ? W[(size_t)k * outc + ncol] : 0.f;
    short h, l;
    f2bf_hilo(v, &h, &l);
    Whi_t[idx] = h;
    Wlo_t[idx] = l;
}

// ---------------- SpMM ----------------
// out[d] = alpha*dinv[d]*sum_e dinv[src]*Xin[src] + beta*Xo[d]
// 32 lanes per node, lane = one float4 of the row. 8x unrolled gather pipeline.

__global__ __launch_bounds__(256) void spmm_kernel(
    float* __restrict__ out, const float* __restrict__ Xin, const float* __restrict__ Xo,
    const float* __restrict__ dinv, const int* __restrict__ rp, const int* __restrict__ cs,
    float alpha, float beta, int n)
{
    int slot = threadIdx.x >> 5;
    int lane = threadIdx.x & 31;
    int node = blockIdx.x * 8 + slot;
    if (node >= n) return;
    const float4* X4 = (const float4*)Xin;
    float4 acc = make_float4(0.f, 0.f, 0.f, 0.f);
    int s = rp[node], e = rp[node + 1];
    int i = s;
    for (; i + 8 <= e; i += 8) {
        int idx[8];
#pragma unroll
        for (int u = 0; u < 8; ++u) idx[u] = cs[i + u];
        float w[8];
#pragma unroll
        for (int u = 0; u < 8; ++u) w[u] = dinv[idx[u]];
        float4 x[8];
#pragma unroll
        for (int u = 0; u < 8; ++u) x[u] = X4[idx[u] * 32 + lane];
#pragma unroll
        for (int u = 0; u < 8; ++u) {
            acc.x += w[u] * x[u].x;
            acc.y += w[u] * x[u].y;
            acc.z += w[u] * x[u].z;
            acc.w += w[u] * x[u].w;
        }
    }
    for (; i < e; ++i) {
        int sc_ = cs[i];
        float w = dinv[sc_];
        float4 x = X4[sc_ * 32 + lane];
        acc.x += w * x.x; acc.y += w * x.y; acc.z += w * x.z; acc.w += w * x.w;
    }
    float sc = alpha * dinv[node];
    float4 r;
    if (beta != 0.f) {
        float4 o = ((const float4*)Xo)[node * 32 + lane];
        r.x = sc * acc.x + beta * o.x;
        r.y = sc * acc.y + beta * o.y;
        r.z = sc * acc.z + beta * o.z;
        r.w = sc * acc.w + beta * o.w;
    } else {
        r.x = sc * acc.x; r.y = sc * acc.y; r.z = sc * acc.z; r.w = sc * acc.w;
    }
    ((float4*)out)[node * 32 + lane] = r;
}

// ---------------- GEMM v3: LDS-free bf16x3 MFMA ----------------
// Block = 256 threads = 4 waves; wave computes 32 rows x NT*16 cols.
// A fragments: fp32 from global (32 B/lane), convert in-register.
// B fragments: precomputed hi/lo bf16 [n][384] from global (L2-hot).

template <int OUTC, int NT>
__global__ __launch_bounds__(256) void gemm_mfma2_kernel(
    float* __restrict__ out, const float* __restrict__ X0, const float* __restrict__ X1,
    const float* __restrict__ X2, const short* __restrict__ Whi_t,
    const short* __restrict__ Wlo_t, const float* __restrict__ bias, int n)
{
    int tid = threadIdx.x;
    int lane = tid & 63;
    int wave = tid >> 6;
    int m15 = lane & 15;
    int quad = lane >> 4;
    int row0 = blockIdx.x * 128 + wave * 32;

    accfrag acc[2][NT];
#pragma unroll
    for (int mi = 0; mi < 2; ++mi)
#pragma unroll
        for (int nj = 0; nj < NT; ++nj) acc[mi][nj] = (accfrag){0.f, 0.f, 0.f, 0.f};

    int r0 = row0 + m15;
    int r1 = row0 + 16 + m15;
    float msk0 = (r0 < n) ? 1.f : 0.f;
    float msk1 = (r1 < n) ? 1.f : 0.f;
    size_t ro0 = (size_t)((r0 < n) ? r0 : 0) * 128;
    size_t ro1 = (size_t)((r1 < n) ? r1 : 0) * 128;

    const float* srcs[3] = { X0, X1, X2 };

    for (int sb = 0; sb < 3; ++sb) {
        const float* Xp = srcs[sb];
#pragma unroll
        for (int kk = 0; kk < 4; ++kk) {
            int k0 = kk * 32 + quad * 8;
            floatx4 f0a = *(const floatx4*)&Xp[ro0 + k0];
            floatx4 f0b = *(const floatx4*)&Xp[ro0 + k0 + 4];
            floatx4 f1a = *(const floatx4*)&Xp[ro1 + k0];
            floatx4 f1b = *(const floatx4*)&Xp[ro1 + k0 + 4];
            f0a *= msk0; f0b *= msk0;
            f1a *= msk1; f1b *= msk1;
            short8_t a_hi[2], a_lo[2];
            cvt8(f0a, f0b, &a_hi[0], &a_lo[0]);
            cvt8(f1a, f1b, &a_hi[1], &a_lo[1]);

            int wk = sb * 128 + k0;
#pragma unroll
            for (int nj = 0; nj < NT; ++nj) {
                int woff = (nj * 16 + m15) * 384 + wk;
                short8_t b_hi = *(const short8_t*)&Whi_t[woff];
                short8_t b_lo = *(const short8_t*)&Wlo_t[woff];
#pragma unroll
                for (int mi = 0; mi < 2; ++mi) {
                    acc[mi][nj] = __builtin_amdgcn_mfma_f32_16x16x32_bf16(a_hi[mi], b_hi, acc[mi][nj], 0, 0, 0);
                    acc[mi][nj] = __builtin_amdgcn_mfma_f32_16x16x32_bf16(a_lo[mi], b_hi, acc[mi][nj], 0, 0, 0);
                    acc[mi][nj] = __builtin_amdgcn_mfma_f32_16x16x32_bf16(a_hi[mi], b_lo, acc[mi][nj], 0, 0, 0);
                }
            }
        }
    }

    // epilogue: bias + relu + store. C/D: col=lane&15, row=quad*4+reg.
#pragma unroll
    for (int nj = 0; nj < NT; ++nj) {
        int col = nj * 16 + m15;
        float bv = (col < OUTC) ? bias[col] : 0.f;
#pragma unroll
        for (int mi = 0; mi < 2; ++mi) {
#pragma unroll
            for (int reg = 0; reg < 4; ++reg) {
                int gr = row0 + mi * 16 + quad * 4 + reg;
                if (gr < n && col < OUTC) {
                    float v = acc[mi][nj][reg] + bv;
                    out[(size_t)gr * OUTC + col] = v > 0.f ? v : 0.f;
                }
            }
        }
    }
}

// ---------------- launch ----------------

extern "C" void kernel_launch(void* const* d_in, const int* in_sizes, int n_in,
                              void* d_out, int out_size, void* d_ws, size_t ws_size,
                              hipStream_t stream) {
    const float* features = (const float*)d_in[0];
    const int*   src      = (const int*)d_in[1];
    const int*   dst      = (const int*)d_in[2];
    const float* W0       = (const float*)d_in[3];
    const float* b0       = (const float*)d_in[4];
    const float* Wh       = (const float*)d_in[5];
    const float* bh       = (const float*)d_in[6];
    const float* Wl       = (const float*)d_in[7];
    const float* bl       = (const float*)d_in[8];
    float* out = (float*)d_out;

    const int N = NN, E = EE;
    const int NB = (N + 255) / 256;
    const int WTOT = 7 * 128 * 384;

    char* ws = (char*)d_ws;
    size_t off = 0;
    auto alloc = [&](size_t bytes) -> void* {
        void* p = ws + off;
        off += (bytes + 511) & ~(size_t)511;
        return p;
    };
    float* dinv   = (float*)alloc((size_t)N * 4);
    int*   rowptr = (int*)alloc((size_t)(N + 1) * 4);
    int*   fill   = (int*)alloc((size_t)N * 4);
    int*   bsum   = (int*)alloc((size_t)NB * 4);
    int*   colsrc = (int*)alloc((size_t)E * 4);
    short* Whi_t  = (short*)alloc((size_t)WTOT * 2);
    short* Wlo_t  = (short*)alloc((size_t)WTOT * 2);
    float* B1     = (float*)alloc((size_t)N * FF * 4);
    float* B2     = (float*)alloc((size_t)N * FF * 4);
    float* XA     = (float*)alloc((size_t)N * FF * 4);
    float* XB     = (float*)alloc((size_t)N * FF * 4);

    // CSR build + W precompute
    hipMemsetAsync(fill, 0, (size_t)N * 4, stream);
    hist_kernel<<<(E + 255) / 256, 256, 0, stream>>>(dst, fill, E);
    wprep_kernel<<<(WTOT + 255) / 256, 256, 0, stream>>>(W0, Wh, Wl, Whi_t, Wlo_t);
    scan_p1_kernel<<<NB, 256, 0, stream>>>(fill, bsum, N);
    scan_p2_kernel<<<1, 1024, 0, stream>>>(bsum, NB);
    scan_p3_kernel<<<NB, 256, 0, stream>>>(fill, bsum, rowptr, N);
    dinv_kernel<<<(N + 255) / 256, 256, 0, stream>>>(rowptr, dinv, N);
    hipMemsetAsync(fill, 0, (size_t)N * 4, stream);
    scatter_kernel<<<(E + 255) / 256, 256, 0, stream>>>(src, dst, rowptr, fill, colsrc, E);

    const float* cur = features;
    float* nxt = XA;
    int spmm_grid = (N + 7) / 8;
    int gemm_grid = (N + 127) / 128;

    for (int layer = 0; layer < 7; ++layer) {
        const float* b;
        bool last = (layer == 6);
        if (layer == 0)      { b = b0; }
        else if (layer < 6)  { b = bh + (layer - 1) * 128; }
        else                 { b = bl; }
        const short* whl = Whi_t + (size_t)layer * 128 * 384;
        const short* wll = Wlo_t + (size_t)layer * 128 * 384;

        spmm_kernel<<<spmm_grid, 256, 0, stream>>>(B1, cur, cur, dinv, rowptr, colsrc, -1.f, 0.f, N);
        spmm_kernel<<<spmm_grid, 256, 0, stream>>>(B2, B1, cur, dinv, rowptr, colsrc, -2.f, -1.f, N);

        float* dstbuf = last ? out : nxt;
        if (!last)
            gemm_mfma2_kernel<128, 8><<<gemm_grid, 256, 0, stream>>>(dstbuf, cur, B1, B2, whl, wll, b, N);
        else
            gemm_mfma2_kernel<40, 3><<<gemm_grid, 256, 0, stream>>>(dstbuf, cur, B1, B2, whl, wll, b, N);

        if (layer < 6) {
            const float* newcur = nxt;
            nxt = (nxt == XA) ? XB : XA;
            cur = newcur;
        }
    }
}

// Round 6
// 2336.538 us; speedup vs baseline: 1.2619x; 1.2619x over previous
//
#include <hip/hip_runtime.h>
#include <hip/hip_bf16.h>

// ChebNet: N=100000, E=1600000, IN=HID=128, OUT=40, K=3, 5 hidden layers.
//  - CSR by dst built per-launch (3-phase multi-block scan).
//  - Per layer: B1 = -spmm(X); B2 = -2*spmm(B1) - X; H = relu([X|B1|B2] @ W + b)
//  - GEMM v4: bf16x3 split MFMA. W precomputed to [ncol][k] hi/lo bf16 once;
//    per-sb 128x128 W slab staged to LDS via contiguous copy (no transpose
//    scatter -> no bank conflicts; row pad to 136 shorts -> uniform 8/bank).
//    A fragments fp32 from global, truncate-hi/round-lo split in-register.

#define NN 100000
#define EE 1600000
#define FF 128

typedef __attribute__((ext_vector_type(8))) short short8_t;
typedef __attribute__((ext_vector_type(4))) float floatx4;
typedef __attribute__((ext_vector_type(4))) float accfrag;

// ---------------- CSR build ----------------

__global__ void hist_kernel(const int* __restrict__ dst, int* __restrict__ cnt, int e) {
    int i = blockIdx.x * blockDim.x + threadIdx.x;
    if (i < e) atomicAdd(&cnt[dst[i]], 1);
}

__global__ __launch_bounds__(256) void scan_p1_kernel(const int* __restrict__ cnt,
                                                      int* __restrict__ bsum, int n) {
    __shared__ int red[8];
    int i = blockIdx.x * 256 + threadIdx.x;
    int v = (i < n) ? cnt[i] : 0;
    for (int off = 32; off > 0; off >>= 1) v += __shfl_down(v, off, 64);
    int wv = threadIdx.x >> 6;
    if ((threadIdx.x & 63) == 0) red[wv] = v;
    __syncthreads();
    if (threadIdx.x == 0) bsum[blockIdx.x] = red[0] + red[1] + red[2] + red[3];
}

__global__ __launch_bounds__(1024) void scan_p2_kernel(int* __restrict__ bsum, int nb) {
    __shared__ int s[1024];
    int tid = threadIdx.x;
    int v = (tid < nb) ? bsum[tid] : 0;
    s[tid] = v;
    __syncthreads();
    for (int off = 1; off < 1024; off <<= 1) {
        int u = (tid >= off) ? s[tid - off] : 0;
        __syncthreads();
        s[tid] += u;
        __syncthreads();
    }
    if (tid < nb) bsum[tid] = s[tid] - v;
}

__global__ __launch_bounds__(256) void scan_p3_kernel(const int* __restrict__ cnt,
                                                      const int* __restrict__ bsum,
                                                      int* __restrict__ row_ptr, int n) {
    __shared__ int s[256];
    int tid = threadIdx.x;
    int i = blockIdx.x * 256 + tid;
    int v = (i < n) ? cnt[i] : 0;
    s[tid] = v;
    __syncthreads();
    for (int off = 1; off < 256; off <<= 1) {
        int u = (tid >= off) ? s[tid - off] : 0;
        __syncthreads();
        s[tid] += u;
        __syncthreads();
    }
    if (i < n) {
        int excl = bsum[blockIdx.x] + s[tid] - v;
        row_ptr[i] = excl;
        if (i == n - 1) row_ptr[n] = excl + v;
    }
}

__global__ void dinv_kernel(const int* __restrict__ row_ptr, float* __restrict__ dinv, int n) {
    int i = blockIdx.x * blockDim.x + threadIdx.x;
    if (i >= n) return;
    int d = row_ptr[i + 1] - row_ptr[i];
    if (d < 1) d = 1;
    dinv[i] = 1.0f / sqrtf((float)d);
}

__global__ void scatter_kernel(const int* __restrict__ src, const int* __restrict__ dst,
                               const int* __restrict__ row_ptr, int* __restrict__ fill,
                               int* __restrict__ col_src, int e) {
    int i = blockIdx.x * blockDim.x + threadIdx.x;
    if (i >= e) return;
    int d = dst[i];
    int pos = row_ptr[d] + atomicAdd(&fill[d], 1);
    col_src[pos] = src[i];
}

// ---------------- fp32 -> bf16 hi/lo splits ----------------

// round-to-nearest both halves (used in wprep, runs once)
__device__ inline void f2bf_hilo(float x, short* hi, short* lo) {
    union { float f; unsigned u; } a; a.f = x;
    unsigned uh = a.u + 0x7FFFu + ((a.u >> 16) & 1u);
    unsigned short h = (unsigned short)(uh >> 16);
    union { unsigned u; float f; } hf; hf.u = ((unsigned)h) << 16;
    float r = x - hf.f;
    union { float f; unsigned u; } b; b.f = r;
    unsigned ul = b.u + 0x7FFFu + ((b.u >> 16) & 1u);
    *hi = (short)h; *lo = (short)(ul >> 16);
}

// cheap split: hi = truncate (exact residual), lo = RTN of residual
__device__ inline void split8(floatx4 a, floatx4 b, short8_t* hi, short8_t* lo) {
    float f[8] = { a.x, a.y, a.z, a.w, b.x, b.y, b.z, b.w };
    short h[8], l[8];
#pragma unroll
    for (int i = 0; i < 8; ++i) {
        union { float f; unsigned u; } x; x.f = f[i];
        unsigned hu = x.u & 0xFFFF0000u;
        h[i] = (short)(hu >> 16);
        union { unsigned u; float f; } hf; hf.u = hu;
        float r = f[i] - hf.f;                 // exact
        union { float f; unsigned u; } rr; rr.f = r;
        unsigned ul = rr.u + 0x7FFFu + ((rr.u >> 16) & 1u);
        l[i] = (short)(ul >> 16);
    }
    *hi = (short8_t){ h[0], h[1], h[2], h[3], h[4], h[5], h[6], h[7] };
    *lo = (short8_t){ l[0], l[1], l[2], l[3], l[4], l[5], l[6], l[7] };
}

// ---------------- W precompute: [layer][ncol(128)][k(384)] hi/lo bf16 ----------------

__global__ __launch_bounds__(256) void wprep_kernel(
    const float* __restrict__ W0, const float* __restrict__ Wh, const float* __restrict__ Wl,
    short* __restrict__ Whi_t, short* __restrict__ Wlo_t)
{
    int idx = blockIdx.x * 256 + threadIdx.x;
    const int PER = 128 * 384;
    if (idx >= 7 * PER) return;
    int layer = idx / PER;
    int rem = idx - layer * PER;
    int ncol = rem / 384;
    int k = rem - ncol * 384;
    const float* W; int outc;
    if (layer == 0)      { W = W0; outc = 128; }
    else if (layer < 6)  { W = Wh + (size_t)(layer - 1) * 384 * 128; outc = 128; }
    else                 { W = Wl; outc = 40; }
    float v = (ncol < outc) ? W[(size_t)k * outc + ncol] : 0.f;
    short h, l;
    f2bf_hilo(v, &h, &l);
    Whi_t[idx] = h;
    Wlo_t[idx] = l;
}

// ---------------- SpMM ----------------

__global__ __launch_bounds__(256) void spmm_kernel(
    float* __restrict__ out, const float* __restrict__ Xin, const float* __restrict__ Xo,
    const float* __restrict__ dinv, const int* __restrict__ rp, const int* __restrict__ cs,
    float alpha, float beta, int n)
{
    int slot = threadIdx.x >> 5;
    int lane = threadIdx.x & 31;
    int node = blockIdx.x * 8 + slot;
    if (node >= n) return;
    const float4* X4 = (const float4*)Xin;
    float4 acc = make_float4(0.f, 0.f, 0.f, 0.f);
    int s = rp[node], e = rp[node + 1];
    int i = s;
    for (; i + 8 <= e; i += 8) {
        int idx[8];
#pragma unroll
        for (int u = 0; u < 8; ++u) idx[u] = cs[i + u];
        float w[8];
#pragma unroll
        for (int u = 0; u < 8; ++u) w[u] = dinv[idx[u]];
        float4 x[8];
#pragma unroll
        for (int u = 0; u < 8; ++u) x[u] = X4[idx[u] * 32 + lane];
#pragma unroll
        for (int u = 0; u < 8; ++u) {
            acc.x += w[u] * x[u].x;
            acc.y += w[u] * x[u].y;
            acc.z += w[u] * x[u].z;
            acc.w += w[u] * x[u].w;
        }
    }
    for (; i < e; ++i) {
        int sc_ = cs[i];
        float w = dinv[sc_];
        float4 x = X4[sc_ * 32 + lane];
        acc.x += w * x.x; acc.y += w * x.y; acc.z += w * x.z; acc.w += w * x.w;
    }
    float sc = alpha * dinv[node];
    float4 r;
    if (beta != 0.f) {
        float4 o = ((const float4*)Xo)[node * 32 + lane];
        r.x = sc * acc.x + beta * o.x;
        r.y = sc * acc.y + beta * o.y;
        r.z = sc * acc.z + beta * o.z;
        r.w = sc * acc.w + beta * o.w;
    } else {
        r.x = sc * acc.x; r.y = sc * acc.y; r.z = sc * acc.z; r.w = sc * acc.w;
    }
    ((float4*)out)[node * 32 + lane] = r;
}

// ---------------- GEMM v4: LDS W-slab bf16x3 MFMA ----------------
// Block = 256 threads = 4 waves; block tile 128 rows x NT*16 cols.
// Per sb: stage W slab [NT*16][128] hi+lo into LDS (contiguous copy, rows
// padded to 136 shorts); fragments read as ds_read_b128 (uniform 8/bank).

template <int OUTC, int NT>
__global__ __launch_bounds__(256, 2) void gemm_mfma3_kernel(
    float* __restrict__ out, const float* __restrict__ X0, const float* __restrict__ X1,
    const float* __restrict__ X2, const short* __restrict__ Whi_t,
    const short* __restrict__ Wlo_t, const float* __restrict__ bias, int n)
{
    __shared__ short Ws[2][NT * 16][136];

    int tid = threadIdx.x;
    int lane = tid & 63;
    int wave = tid >> 6;
    int m15 = lane & 15;
    int quad = lane >> 4;
    int row0 = blockIdx.x * 128 + wave * 32;

    accfrag acc[2][NT];
#pragma unroll
    for (int mi = 0; mi < 2; ++mi)
#pragma unroll
        for (int nj = 0; nj < NT; ++nj) acc[mi][nj] = (accfrag){0.f, 0.f, 0.f, 0.f};

    int r0 = row0 + m15;
    int r1 = r0 + 16;
    float msk0 = (r0 < n) ? 1.f : 0.f;
    float msk1 = (r1 < n) ? 1.f : 0.f;
    size_t ro0 = (size_t)((r0 < n) ? r0 : 0) * 128;
    size_t ro1 = (size_t)((r1 < n) ? r1 : 0) * 128;

    const float* srcs[3] = { X0, X1, X2 };

    for (int sb = 0; sb < 3; ++sb) {
        // ---- stage W slab: NT*16 rows x 128 shorts, hi then lo ----
        {
            const int VEC = NT * 512;          // short8 copies across both arrays
#pragma unroll
            for (int v0 = 0; v0 < VEC; v0 += 256) {
                int v = v0 + tid;
                int a = (v >= NT * 256) ? 1 : 0;
                int rem = v - a * (NT * 256);
                int row = rem >> 4;
                int c8 = (rem & 15) * 8;
                const short* g = (a ? Wlo_t : Whi_t) + (size_t)row * 384 + sb * 128 + c8;
                *(short8_t*)&Ws[a][row][c8] = *(const short8_t*)g;
            }
        }
        __syncthreads();

        const float* Xp = srcs[sb];
#pragma unroll
        for (int kk = 0; kk < 4; ++kk) {
            int k0 = kk * 32 + quad * 8;
            floatx4 f0a = *(const floatx4*)&Xp[ro0 + k0];
            floatx4 f0b = *(const floatx4*)&Xp[ro0 + k0 + 4];
            floatx4 f1a = *(const floatx4*)&Xp[ro1 + k0];
            floatx4 f1b = *(const floatx4*)&Xp[ro1 + k0 + 4];
            f0a *= msk0; f0b *= msk0;
            f1a *= msk1; f1b *= msk1;
            short8_t a_hi[2], a_lo[2];
            split8(f0a, f0b, &a_hi[0], &a_lo[0]);
            split8(f1a, f1b, &a_hi[1], &a_lo[1]);

#pragma unroll
            for (int nj = 0; nj < NT; ++nj) {
                short8_t b_hi = *(const short8_t*)&Ws[0][nj * 16 + m15][k0];
                short8_t b_lo = *(const short8_t*)&Ws[1][nj * 16 + m15][k0];
#pragma unroll
                for (int mi = 0; mi < 2; ++mi) {
                    acc[mi][nj] = __builtin_amdgcn_mfma_f32_16x16x32_bf16(a_hi[mi], b_hi, acc[mi][nj], 0, 0, 0);
                    acc[mi][nj] = __builtin_amdgcn_mfma_f32_16x16x32_bf16(a_lo[mi], b_hi, acc[mi][nj], 0, 0, 0);
                    acc[mi][nj] = __builtin_amdgcn_mfma_f32_16x16x32_bf16(a_hi[mi], b_lo, acc[mi][nj], 0, 0, 0);
                }
            }
        }
        __syncthreads();
    }

    // epilogue: bias + relu + store. C/D: col=lane&15, row=quad*4+reg.
#pragma unroll
    for (int nj = 0; nj < NT; ++nj) {
        int col = nj * 16 + m15;
        float bv = (col < OUTC) ? bias[col] : 0.f;
#pragma unroll
        for (int mi = 0; mi < 2; ++mi) {
#pragma unroll
            for (int reg = 0; reg < 4; ++reg) {
                int gr = row0 + mi * 16 + quad * 4 + reg;
                if (gr < n && col < OUTC) {
                    float v = acc[mi][nj][reg] + bv;
                    out[(size_t)gr * OUTC + col] = v > 0.f ? v : 0.f;
                }
            }
        }
    }
}

// ---------------- launch ----------------

extern "C" void kernel_launch(void* const* d_in, const int* in_sizes, int n_in,
                              void* d_out, int out_size, void* d_ws, size_t ws_size,
                              hipStream_t stream) {
    const float* features = (const float*)d_in[0];
    const int*   src      = (const int*)d_in[1];
    const int*   dst      = (const int*)d_in[2];
    const float* W0       = (const float*)d_in[3];
    const float* b0       = (const float*)d_in[4];
    const float* Wh       = (const float*)d_in[5];
    const float* bh       = (const float*)d_in[6];
    const float* Wl       = (const float*)d_in[7];
    const float* bl       = (const float*)d_in[8];
    float* out = (float*)d_out;

    const int N = NN, E = EE;
    const int NB = (N + 255) / 256;
    const int WTOT = 7 * 128 * 384;

    char* ws = (char*)d_ws;
    size_t off = 0;
    auto alloc = [&](size_t bytes) -> void* {
        void* p = ws + off;
        off += (bytes + 511) & ~(size_t)511;
        return p;
    };
    float* dinv   = (float*)alloc((size_t)N * 4);
    int*   rowptr = (int*)alloc((size_t)(N + 1) * 4);
    int*   fill   = (int*)alloc((size_t)N * 4);
    int*   bsum   = (int*)alloc((size_t)NB * 4);
    int*   colsrc = (int*)alloc((size_t)E * 4);
    short* Whi_t  = (short*)alloc((size_t)WTOT * 2);
    short* Wlo_t  = (short*)alloc((size_t)WTOT * 2);
    float* B1     = (float*)alloc((size_t)N * FF * 4);
    float* B2     = (float*)alloc((size_t)N * FF * 4);
    float* XA     = (float*)alloc((size_t)N * FF * 4);
    float* XB     = (float*)alloc((size_t)N * FF * 4);

    // CSR build + W precompute
    hipMemsetAsync(fill, 0, (size_t)N * 4, stream);
    hist_kernel<<<(E + 255) / 256, 256, 0, stream>>>(dst, fill, E);
    wprep_kernel<<<(WTOT + 255) / 256, 256, 0, stream>>>(W0, Wh, Wl, Whi_t, Wlo_t);
    scan_p1_kernel<<<NB, 256, 0, stream>>>(fill, bsum, N);
    scan_p2_kernel<<<1, 1024, 0, stream>>>(bsum, NB);
    scan_p3_kernel<<<NB, 256, 0, stream>>>(fill, bsum, rowptr, N);
    dinv_kernel<<<(N + 255) / 256, 256, 0, stream>>>(rowptr, dinv, N);
    hipMemsetAsync(fill, 0, (size_t)N * 4, stream);
    scatter_kernel<<<(E + 255) / 256, 256, 0, stream>>>(src, dst, rowptr, fill, colsrc, E);

    const float* cur = features;
    float* nxt = XA;
    int spmm_grid = (N + 7) / 8;
    int gemm_grid = (N + 127) / 128;

    for (int layer = 0; layer < 7; ++layer) {
        const float* b;
        bool last = (layer == 6);
        if (layer == 0)      { b = b0; }
        else if (layer < 6)  { b = bh + (layer - 1) * 128; }
        else                 { b = bl; }
        const short* whl = Whi_t + (size_t)layer * 128 * 384;
        const short* wll = Wlo_t + (size_t)layer * 128 * 384;

        spmm_kernel<<<spmm_grid, 256, 0, stream>>>(B1, cur, cur, dinv, rowptr, colsrc, -1.f, 0.f, N);
        spmm_kernel<<<spmm_grid, 256, 0, stream>>>(B2, B1, cur, dinv, rowptr, colsrc, -2.f, -1.f, N);

        float* dstbuf = last ? out : nxt;
        if (!last)
            gemm_mfma3_kernel<128, 8><<<gemm_grid, 256, 0, stream>>>(dstbuf, cur, B1, B2, whl, wll, b, N);
        else
            gemm_mfma3_kernel<40, 3><<<gemm_grid, 256, 0, stream>>>(dstbuf, cur, B1, B2, whl, wll, b, N);

        if (layer < 6) {
            const float* newcur = nxt;
            nxt = (nxt == XA) ? XB : XA;
            cur = newcur;
        }
    }
}

// Round 7
// 1580.423 us; speedup vs baseline: 1.8656x; 1.4784x over previous
//
#include <hip/hip_runtime.h>
#include <hip/hip_bf16.h>

// ChebNet: N=100000, E=1600000, IN=HID=128, OUT=40, K=3, 5 hidden layers.
//  v5: all activations stored fp16 (halves gather + A-operand traffic; fp16
//  splits exactly into bf16 hi+lo so the bf16x3 MFMA GEMM stays exact on them).
//  - CSR by dst built per-launch (3-phase multi-block scan).
//  - Per layer: B1 = -spmm(X); B2 = -2*spmm(B1) - X; H = relu([X|B1|B2] @ W + b)
//  - SpMM: 16 lanes/node, 16B fp16 loads, fp32 accumulate, fp16 store.
//  - GEMM: W precomputed [ncol][k] hi/lo bf16; per-sb slab staged to LDS by
//    contiguous copy (no conflicts); A fp16 -> exact bf16 hi/lo in-register.

#define NN 100000
#define EE 1600000
#define FF 128

typedef __attribute__((ext_vector_type(8))) short short8_t;
typedef __attribute__((ext_vector_type(8))) _Float16 half8_t;
typedef __attribute__((ext_vector_type(4))) float floatx4;
typedef __attribute__((ext_vector_type(4))) float accfrag;

// ---------------- CSR build ----------------

__global__ void hist_kernel(const int* __restrict__ dst, int* __restrict__ cnt, int e) {
    int i = blockIdx.x * blockDim.x + threadIdx.x;
    if (i < e) atomicAdd(&cnt[dst[i]], 1);
}

__global__ __launch_bounds__(256) void scan_p1_kernel(const int* __restrict__ cnt,
                                                      int* __restrict__ bsum, int n) {
    __shared__ int red[8];
    int i = blockIdx.x * 256 + threadIdx.x;
    int v = (i < n) ? cnt[i] : 0;
    for (int off = 32; off > 0; off >>= 1) v += __shfl_down(v, off, 64);
    int wv = threadIdx.x >> 6;
    if ((threadIdx.x & 63) == 0) red[wv] = v;
    __syncthreads();
    if (threadIdx.x == 0) bsum[blockIdx.x] = red[0] + red[1] + red[2] + red[3];
}

__global__ __launch_bounds__(1024) void scan_p2_kernel(int* __restrict__ bsum, int nb) {
    __shared__ int s[1024];
    int tid = threadIdx.x;
    int v = (tid < nb) ? bsum[tid] : 0;
    s[tid] = v;
    __syncthreads();
    for (int off = 1; off < 1024; off <<= 1) {
        int u = (tid >= off) ? s[tid - off] : 0;
        __syncthreads();
        s[tid] += u;
        __syncthreads();
    }
    if (tid < nb) bsum[tid] = s[tid] - v;
}

__global__ __launch_bounds__(256) void scan_p3_kernel(const int* __restrict__ cnt,
                                                      const int* __restrict__ bsum,
                                                      int* __restrict__ row_ptr, int n) {
    __shared__ int s[256];
    int tid = threadIdx.x;
    int i = blockIdx.x * 256 + tid;
    int v = (i < n) ? cnt[i] : 0;
    s[tid] = v;
    __syncthreads();
    for (int off = 1; off < 256; off <<= 1) {
        int u = (tid >= off) ? s[tid - off] : 0;
        __syncthreads();
        s[tid] += u;
        __syncthreads();
    }
    if (i < n) {
        int excl = bsum[blockIdx.x] + s[tid] - v;
        row_ptr[i] = excl;
        if (i == n - 1) row_ptr[n] = excl + v;
    }
}

__global__ void dinv_kernel(const int* __restrict__ row_ptr, float* __restrict__ dinv, int n) {
    int i = blockIdx.x * blockDim.x + threadIdx.x;
    if (i >= n) return;
    int d = row_ptr[i + 1] - row_ptr[i];
    if (d < 1) d = 1;
    dinv[i] = 1.0f / sqrtf((float)d);
}

__global__ void scatter_kernel(const int* __restrict__ src, const int* __restrict__ dst,
                               const int* __restrict__ row_ptr, int* __restrict__ fill,
                               int* __restrict__ col_src, int e) {
    int i = blockIdx.x * blockDim.x + threadIdx.x;
    if (i >= e) return;
    int d = dst[i];
    int pos = row_ptr[d] + atomicAdd(&fill[d], 1);
    col_src[pos] = src[i];
}

// ---------------- fp32 -> fp16 feature convert ----------------

__global__ __launch_bounds__(256) void fcvt_kernel(const float* __restrict__ in,
                                                   _Float16* __restrict__ out, int total4) {
    int i = blockIdx.x * 256 + threadIdx.x;
    if (i >= total4) return;
    floatx4 v = *(const floatx4*)&in[i * 4];
    _Float16 r[4] = { (_Float16)v.x, (_Float16)v.y, (_Float16)v.z, (_Float16)v.w };
    *(__attribute__((ext_vector_type(4))) _Float16*)&out[i * 4] =
        (__attribute__((ext_vector_type(4))) _Float16){ r[0], r[1], r[2], r[3] };
}

// ---------------- fp32 -> bf16 hi/lo splits ----------------

__device__ inline void f2bf_hilo(float x, short* hi, short* lo) {
    union { float f; unsigned u; } a; a.f = x;
    unsigned uh = a.u + 0x7FFFu + ((a.u >> 16) & 1u);
    unsigned short h = (unsigned short)(uh >> 16);
    union { unsigned u; float f; } hf; hf.u = ((unsigned)h) << 16;
    float r = x - hf.f;
    union { float f; unsigned u; } b; b.f = r;
    unsigned ul = b.u + 0x7FFFu + ((b.u >> 16) & 1u);
    *hi = (short)h; *lo = (short)(ul >> 16);
}

// truncate-hi / exact-residual-lo split (exact for fp16-backed values)
__device__ inline void split8a(const float* f, short8_t* hi, short8_t* lo) {
    short h[8], l[8];
#pragma unroll
    for (int i = 0; i < 8; ++i) {
        union { float f; unsigned u; } x; x.f = f[i];
        unsigned hu = x.u & 0xFFFF0000u;
        h[i] = (short)(hu >> 16);
        union { unsigned u; float f; } hf; hf.u = hu;
        float r = f[i] - hf.f;                 // exact
        union { float f; unsigned u; } rr; rr.f = r;
        unsigned ul = rr.u + 0x7FFFu + ((rr.u >> 16) & 1u);
        l[i] = (short)(ul >> 16);
    }
    *hi = (short8_t){ h[0], h[1], h[2], h[3], h[4], h[5], h[6], h[7] };
    *lo = (short8_t){ l[0], l[1], l[2], l[3], l[4], l[5], l[6], l[7] };
}

// ---------------- W precompute: [layer][ncol(128)][k(384)] hi/lo bf16 ----------------

__global__ __launch_bounds__(256) void wprep_kernel(
    const float* __restrict__ W0, const float* __restrict__ Wh, const float* __restrict__ Wl,
    short* __restrict__ Whi_t, short* __restrict__ Wlo_t)
{
    int idx = blockIdx.x * 256 + threadIdx.x;
    const int PER = 128 * 384;
    if (idx >= 7 * PER) return;
    int layer = idx / PER;
    int rem = idx - layer * PER;
    int ncol = rem / 384;
    int k = rem - ncol * 384;
    const float* W; int outc;
    if (layer == 0)      { W = W0; outc = 128; }
    else if (layer < 6)  { W = Wh + (size_t)(layer - 1) * 384 * 128; outc = 128; }
    else                 { W = Wl; outc = 40; }
    float v = (ncol < outc) ? W[(size_t)k * outc + ncol] : 0.f;
    short h, l;
    f2bf_hilo(v, &h, &l);
    Whi_t[idx] = h;
    Wlo_t[idx] = l;
}

// ---------------- SpMM (fp16 rows) ----------------
// out[d] = alpha*dinv[d]*sum_e dinv[src]*Xin[src] + beta*Xo[d]
// 16 lanes per node; lane = one half8 (16B) of the 256B row. fp32 accumulate.

__global__ __launch_bounds__(256) void spmm_h_kernel(
    _Float16* __restrict__ out, const _Float16* __restrict__ Xin,
    const _Float16* __restrict__ Xo, const float* __restrict__ dinv,
    const int* __restrict__ rp, const int* __restrict__ cs,
    float alpha, float beta, int n)
{
    int slot = threadIdx.x >> 4;
    int lane = threadIdx.x & 15;
    int node = blockIdx.x * 16 + slot;
    if (node >= n) return;
    const half8_t* X8 = (const half8_t*)Xin;
    float acc[8] = { 0.f, 0.f, 0.f, 0.f, 0.f, 0.f, 0.f, 0.f };
    int s = rp[node], e = rp[node + 1];
    int i = s;
    for (; i + 8 <= e; i += 8) {
        int idx[8];
#pragma unroll
        for (int u = 0; u < 8; ++u) idx[u] = cs[i + u];
        float w[8];
#pragma unroll
        for (int u = 0; u < 8; ++u) w[u] = dinv[idx[u]];
        half8_t x[8];
#pragma unroll
        for (int u = 0; u < 8; ++u) x[u] = X8[(size_t)idx[u] * 16 + lane];
#pragma unroll
        for (int u = 0; u < 8; ++u)
#pragma unroll
            for (int j = 0; j < 8; ++j) acc[j] += w[u] * (float)x[u][j];
    }
    for (; i < e; ++i) {
        int sidx = cs[i];
        float w = dinv[sidx];
        half8_t x = X8[(size_t)sidx * 16 + lane];
#pragma unroll
        for (int j = 0; j < 8; ++j) acc[j] += w * (float)x[j];
    }
    float sc = alpha * dinv[node];
    half8_t r;
    if (beta != 0.f) {
        half8_t o = ((const half8_t*)Xo)[(size_t)node * 16 + lane];
#pragma unroll
        for (int j = 0; j < 8; ++j) r[j] = (_Float16)(sc * acc[j] + beta * (float)o[j]);
    } else {
#pragma unroll
        for (int j = 0; j < 8; ++j) r[j] = (_Float16)(sc * acc[j]);
    }
    ((half8_t*)out)[(size_t)node * 16 + lane] = r;
}

// ---------------- GEMM: LDS W-slab bf16x3 MFMA, fp16 A ----------------
// Block = 256 threads = 4 waves; block tile 128 rows x NT*16 cols.

template <int OUTC, int NT, bool HOUT>
__global__ __launch_bounds__(256, 2) void gemm_mfma4_kernel(
    void* __restrict__ outp, const _Float16* __restrict__ X0,
    const _Float16* __restrict__ X1, const _Float16* __restrict__ X2,
    const short* __restrict__ Whi_t, const short* __restrict__ Wlo_t,
    const float* __restrict__ bias, int n)
{
    __shared__ short Ws[2][NT * 16][136];

    int tid = threadIdx.x;
    int lane = tid & 63;
    int wave = tid >> 6;
    int m15 = lane & 15;
    int quad = lane >> 4;
    int row0 = blockIdx.x * 128 + wave * 32;

    accfrag acc[2][NT];
#pragma unroll
    for (int mi = 0; mi < 2; ++mi)
#pragma unroll
        for (int nj = 0; nj < NT; ++nj) acc[mi][nj] = (accfrag){0.f, 0.f, 0.f, 0.f};

    int r0 = row0 + m15;
    int r1 = r0 + 16;
    float msk0 = (r0 < n) ? 1.f : 0.f;
    float msk1 = (r1 < n) ? 1.f : 0.f;
    size_t ro0 = (size_t)((r0 < n) ? r0 : 0) * 16;   // in half8 units
    size_t ro1 = (size_t)((r1 < n) ? r1 : 0) * 16;

    const _Float16* srcs[3] = { X0, X1, X2 };

    for (int sb = 0; sb < 3; ++sb) {
        // ---- stage W slab: NT*16 rows x 128 shorts, hi then lo (contiguous) ----
        {
            const int VEC = NT * 512;
#pragma unroll
            for (int v0 = 0; v0 < VEC; v0 += 256) {
                int v = v0 + tid;
                int a = (v >= NT * 256) ? 1 : 0;
                int rem = v - a * (NT * 256);
                int row = rem >> 4;
                int c8 = (rem & 15) * 8;
                const short* g = (a ? Wlo_t : Whi_t) + (size_t)row * 384 + sb * 128 + c8;
                *(short8_t*)&Ws[a][row][c8] = *(const short8_t*)g;
            }
        }
        __syncthreads();

        const half8_t* Xp8 = (const half8_t*)srcs[sb];
#pragma unroll
        for (int kk = 0; kk < 4; ++kk) {
            int k0 = kk * 32 + quad * 8;
            half8_t h0 = Xp8[ro0 + kk * 4 + quad];
            half8_t h1 = Xp8[ro1 + kk * 4 + quad];
            float f0[8], f1[8];
#pragma unroll
            for (int j = 0; j < 8; ++j) { f0[j] = msk0 * (float)h0[j]; f1[j] = msk1 * (float)h1[j]; }
            short8_t a_hi[2], a_lo[2];
            split8a(f0, &a_hi[0], &a_lo[0]);
            split8a(f1, &a_hi[1], &a_lo[1]);

#pragma unroll
            for (int nj = 0; nj < NT; ++nj) {
                short8_t b_hi = *(const short8_t*)&Ws[0][nj * 16 + m15][k0];
                short8_t b_lo = *(const short8_t*)&Ws[1][nj * 16 + m15][k0];
#pragma unroll
                for (int mi = 0; mi < 2; ++mi) {
                    acc[mi][nj] = __builtin_amdgcn_mfma_f32_16x16x32_bf16(a_hi[mi], b_hi, acc[mi][nj], 0, 0, 0);
                    acc[mi][nj] = __builtin_amdgcn_mfma_f32_16x16x32_bf16(a_lo[mi], b_hi, acc[mi][nj], 0, 0, 0);
                    acc[mi][nj] = __builtin_amdgcn_mfma_f32_16x16x32_bf16(a_hi[mi], b_lo, acc[mi][nj], 0, 0, 0);
                }
            }
        }
        __syncthreads();
    }

    // epilogue: bias + relu + store. C/D: col=lane&15, row=quad*4+reg.
#pragma unroll
    for (int nj = 0; nj < NT; ++nj) {
        int col = nj * 16 + m15;
        float bv = (col < OUTC) ? bias[col] : 0.f;
#pragma unroll
        for (int mi = 0; mi < 2; ++mi) {
#pragma unroll
            for (int reg = 0; reg < 4; ++reg) {
                int gr = row0 + mi * 16 + quad * 4 + reg;
                if (gr < n && col < OUTC) {
                    float v = acc[mi][nj][reg] + bv;
                    v = v > 0.f ? v : 0.f;
                    if (HOUT) ((_Float16*)outp)[(size_t)gr * OUTC + col] = (_Float16)v;
                    else      ((float*)outp)[(size_t)gr * OUTC + col] = v;
                }
            }
        }
    }
}

// ---------------- launch ----------------

extern "C" void kernel_launch(void* const* d_in, const int* in_sizes, int n_in,
                              void* d_out, int out_size, void* d_ws, size_t ws_size,
                              hipStream_t stream) {
    const float* features = (const float*)d_in[0];
    const int*   src      = (const int*)d_in[1];
    const int*   dst      = (const int*)d_in[2];
    const float* W0       = (const float*)d_in[3];
    const float* b0       = (const float*)d_in[4];
    const float* Wh       = (const float*)d_in[5];
    const float* bh       = (const float*)d_in[6];
    const float* Wl       = (const float*)d_in[7];
    const float* bl       = (const float*)d_in[8];
    float* out = (float*)d_out;

    const int N = NN, E = EE;
    const int NB = (N + 255) / 256;
    const int WTOT = 7 * 128 * 384;

    char* ws = (char*)d_ws;
    size_t off = 0;
    auto alloc = [&](size_t bytes) -> void* {
        void* p = ws + off;
        off += (bytes + 511) & ~(size_t)511;
        return p;
    };
    float*    dinv   = (float*)alloc((size_t)N * 4);
    int*      rowptr = (int*)alloc((size_t)(N + 1) * 4);
    int*      fill   = (int*)alloc((size_t)N * 4);
    int*      bsum   = (int*)alloc((size_t)NB * 4);
    int*      colsrc = (int*)alloc((size_t)E * 4);
    short*    Whi_t  = (short*)alloc((size_t)WTOT * 2);
    short*    Wlo_t  = (short*)alloc((size_t)WTOT * 2);
    _Float16* XA     = (_Float16*)alloc((size_t)N * FF * 2);
    _Float16* XB     = (_Float16*)alloc((size_t)N * FF * 2);
    _Float16* B1     = (_Float16*)alloc((size_t)N * FF * 2);
    _Float16* B2     = (_Float16*)alloc((size_t)N * FF * 2);

    // CSR build + W precompute + feature convert
    hipMemsetAsync(fill, 0, (size_t)N * 4, stream);
    hist_kernel<<<(E + 255) / 256, 256, 0, stream>>>(dst, fill, E);
    wprep_kernel<<<(WTOT + 255) / 256, 256, 0, stream>>>(W0, Wh, Wl, Whi_t, Wlo_t);
    fcvt_kernel<<<(N * FF / 4 + 255) / 256, 256, 0, stream>>>(features, XA, N * FF / 4);
    scan_p1_kernel<<<NB, 256, 0, stream>>>(fill, bsum, N);
    scan_p2_kernel<<<1, 1024, 0, stream>>>(bsum, NB);
    scan_p3_kernel<<<NB, 256, 0, stream>>>(fill, bsum, rowptr, N);
    dinv_kernel<<<(N + 255) / 256, 256, 0, stream>>>(rowptr, dinv, N);
    hipMemsetAsync(fill, 0, (size_t)N * 4, stream);
    scatter_kernel<<<(E + 255) / 256, 256, 0, stream>>>(src, dst, rowptr, fill, colsrc, E);

    const _Float16* cur = XA;
    _Float16* nxt = XB;
    int spmm_grid = (N + 15) / 16;
    int gemm_grid = (N + 127) / 128;

    for (int layer = 0; layer < 7; ++layer) {
        const float* b;
        bool last = (layer == 6);
        if (layer == 0)      { b = b0; }
        else if (layer < 6)  { b = bh + (layer - 1) * 128; }
        else                 { b = bl; }
        const short* whl = Whi_t + (size_t)layer * 128 * 384;
        const short* wll = Wlo_t + (size_t)layer * 128 * 384;

        spmm_h_kernel<<<spmm_grid, 256, 0, stream>>>(B1, cur, cur, dinv, rowptr, colsrc, -1.f, 0.f, N);
        spmm_h_kernel<<<spmm_grid, 256, 0, stream>>>(B2, B1, cur, dinv, rowptr, colsrc, -2.f, -1.f, N);

        if (!last)
            gemm_mfma4_kernel<128, 8, true><<<gemm_grid, 256, 0, stream>>>((void*)nxt, cur, B1, B2, whl, wll, b, N);
        else
            gemm_mfma4_kernel<40, 3, false><<<gemm_grid, 256, 0, stream>>>((void*)out, cur, B1, B2, whl, wll, b, N);

        if (layer < 6) {
            const _Float16* newcur = nxt;
            nxt = (_Float16*)((nxt == XB) ? XA : XB);
            cur = newcur;
        }
    }
}

// Round 8
// 1436.955 us; speedup vs baseline: 2.0519x; 1.0998x over previous
//
#include <hip/hip_runtime.h>
#include <hip/hip_bf16.h>

// ChebNet: N=100000, E=1600000, IN=HID=128, OUT=40, K=3, 5 hidden layers.
//  v6: - activations stored fp16 in SCALED space Z = dinv .* Y  ->  spmm is a
//        pure gather-sum (no per-edge dinv load); GEMM rescales by sdeg=sqrt(deg).
//      - bucketed CSR build (bucket = dst>>6): LDS-aggregated hist + scatter of
//        packed 4B records, then per-bucket LDS counting sort -> coalesced writes.
//      - GEMM: bf16x3 split MFMA, W precomputed [ncol][k] hi/lo, LDS slab copy.

#define NN 100000
#define EE 1600000
#define FF 128
#define NBK 1563           // (NN+63)>>6
#define EPB 4096           // edges per block in bucket passes
#define CAP 3072           // per-bucket staging capacity (mean 1024, sigma 32)

typedef __attribute__((ext_vector_type(8))) short short8_t;
typedef __attribute__((ext_vector_type(8))) _Float16 half8_t;
typedef __attribute__((ext_vector_type(4))) _Float16 half4_t;
typedef __attribute__((ext_vector_type(4))) float floatx4;
typedef __attribute__((ext_vector_type(4))) float accfrag;

// ---------------- bucketed CSR build ----------------

__global__ __launch_bounds__(256) void bhist_kernel(const int* __restrict__ dst,
                                                    int* __restrict__ bcnt) {
    __shared__ int lh[NBK];
    int tid = threadIdx.x;
    for (int j = tid; j < NBK; j += 256) lh[j] = 0;
    __syncthreads();
    int e0 = blockIdx.x * EPB;
#pragma unroll
    for (int k = 0; k < EPB / 256; ++k) {
        int i = e0 + k * 256 + tid;
        if (i < EE) atomicAdd(&lh[dst[i] >> 6], 1);
    }
    __syncthreads();
    for (int j = tid; j < NBK; j += 256)
        if (lh[j] > 0) atomicAdd(&bcnt[j], lh[j]);
}

// 3-phase scan (reused over NBK bucket counts)
__global__ __launch_bounds__(256) void scan_p1_kernel(const int* __restrict__ cnt,
                                                      int* __restrict__ bsum, int n) {
    __shared__ int red[8];
    int i = blockIdx.x * 256 + threadIdx.x;
    int v = (i < n) ? cnt[i] : 0;
    for (int off = 32; off > 0; off >>= 1) v += __shfl_down(v, off, 64);
    int wv = threadIdx.x >> 6;
    if ((threadIdx.x & 63) == 0) red[wv] = v;
    __syncthreads();
    if (threadIdx.x == 0) bsum[blockIdx.x] = red[0] + red[1] + red[2] + red[3];
}

__global__ __launch_bounds__(1024) void scan_p2_kernel(int* __restrict__ bsum, int nb) {
    __shared__ int s[1024];
    int tid = threadIdx.x;
    int v = (tid < nb) ? bsum[tid] : 0;
    s[tid] = v;
    __syncthreads();
    for (int off = 1; off < 1024; off <<= 1) {
        int u = (tid >= off) ? s[tid - off] : 0;
        __syncthreads();
        s[tid] += u;
        __syncthreads();
    }
    if (tid < nb) bsum[tid] = s[tid] - v;
}

__global__ __launch_bounds__(256) void scan_p3_kernel(const int* __restrict__ cnt,
                                                      const int* __restrict__ bsum,
                                                      int* __restrict__ out_ptr, int n) {
    __shared__ int s[256];
    int tid = threadIdx.x;
    int i = blockIdx.x * 256 + tid;
    int v = (i < n) ? cnt[i] : 0;
    s[tid] = v;
    __syncthreads();
    for (int off = 1; off < 256; off <<= 1) {
        int u = (tid >= off) ? s[tid - off] : 0;
        __syncthreads();
        s[tid] += u;
        __syncthreads();
    }
    if (i < n) {
        int excl = bsum[blockIdx.x] + s[tid] - v;
        out_ptr[i] = excl;
        if (i == n - 1) out_ptr[n] = excl + v;
    }
}

// scatter packed (src<<6 | dstoff) into bucket regions, LDS-aggregated reservation
__global__ __launch_bounds__(256) void bscatter_kernel(
    const int* __restrict__ src, const int* __restrict__ dst,
    const int* __restrict__ bptr, int* __restrict__ bfill, int* __restrict__ ebuf) {
    __shared__ int lh[NBK];
    __shared__ int lbase[NBK];
    int tid = threadIdx.x;
    for (int j = tid; j < NBK; j += 256) lh[j] = 0;
    __syncthreads();
    int e0 = blockIdx.x * EPB;
#pragma unroll
    for (int k = 0; k < EPB / 256; ++k) {
        int i = e0 + k * 256 + tid;
        if (i < EE) atomicAdd(&lh[dst[i] >> 6], 1);
    }
    __syncthreads();
    for (int j = tid; j < NBK; j += 256)
        if (lh[j] > 0) lbase[j] = atomicAdd(&bfill[j], lh[j]);
    __syncthreads();
    for (int j = tid; j < NBK; j += 256) lh[j] = 0;
    __syncthreads();
#pragma unroll
    for (int k = 0; k < EPB / 256; ++k) {
        int i = e0 + k * 256 + tid;
        if (i < EE) {
            int d = dst[i];
            int b = d >> 6;
            int off = atomicAdd(&lh[b], 1);
            ebuf[bptr[b] + lbase[b] + off] = (src[i] << 6) | (d & 63);
        }
    }
}

// per-bucket LDS counting sort -> colsrc, rowptr, and degree-derived scales
__global__ __launch_bounds__(256) void csr_build_kernel(
    const int* __restrict__ ebuf, const int* __restrict__ bptr,
    int* __restrict__ rowptr, int* __restrict__ colsrc,
    float* __restrict__ dinv, float* __restrict__ dinv2, float* __restrict__ sdeg) {
    __shared__ int pk[CAP];
    __shared__ int ob[CAP];
    __shared__ int cnt[64];
    __shared__ int sexcl[64];
    __shared__ int fill[64];

    int tid = threadIdx.x;
    int b = blockIdx.x;
    int start = bptr[b];
    int cb = bptr[b + 1] - start;
    if (cb > CAP) cb = CAP;   // statistically impossible for this dataset

    if (tid < 64) { cnt[tid] = 0; fill[tid] = 0; }
    __syncthreads();

    for (int i = tid; i < cb; i += 256) {
        int v = ebuf[start + i];
        pk[i] = v;
        atomicAdd(&cnt[v & 63], 1);
    }
    __syncthreads();

    if (tid < 64) {
        int v = cnt[tid];
        int inc = v;
        for (int off = 1; off < 64; off <<= 1) {
            int u = __shfl_up(inc, off, 64);
            if (tid >= off) inc += u;
        }
        int excl = inc - v;
        sexcl[tid] = excl;
        int gnode = b * 64 + tid;
        if (gnode < NN) {
            rowptr[gnode] = start + excl;
            int d = v < 1 ? 1 : v;
            float fd = (float)d;
            dinv[gnode]  = 1.0f / sqrtf(fd);
            dinv2[gnode] = 1.0f / fd;
            sdeg[gnode]  = sqrtf(fd);
        }
    }
    if (b == 0 && tid == 0) rowptr[NN] = EE;
    __syncthreads();

    for (int i = tid; i < cb; i += 256) {
        int v = pk[i];
        int d = v & 63;
        int off = atomicAdd(&fill[d], 1);
        ob[sexcl[d] + off] = v >> 6;
    }
    __syncthreads();

    for (int i = tid; i < cb; i += 256) colsrc[start + i] = ob[i];
}

// ---------------- fp32 -> bf16 hi/lo split (round both) ----------------

__device__ inline void f2bf_hilo(float x, short* hi, short* lo) {
    union { float f; unsigned u; } a; a.f = x;
    unsigned uh = a.u + 0x7FFFu + ((a.u >> 16) & 1u);
    unsigned short h = (unsigned short)(uh >> 16);
    union { unsigned u; float f; } hf; hf.u = ((unsigned)h) << 16;
    float r = x - hf.f;
    union { float f; unsigned u; } b; b.f = r;
    unsigned ul = b.u + 0x7FFFu + ((b.u >> 16) & 1u);
    *hi = (short)h; *lo = (short)(ul >> 16);
}

// truncate-hi / RTN-residual-lo split (residual exact; total err ~2^-17 rel)
__device__ inline void split8a(const float* f, short8_t* hi, short8_t* lo) {
    short h[8], l[8];
#pragma unroll
    for (int i = 0; i < 8; ++i) {
        union { float f; unsigned u; } x; x.f = f[i];
        unsigned hu = x.u & 0xFFFF0000u;
        h[i] = (short)(hu >> 16);
        union { unsigned u; float f; } hf; hf.u = hu;
        float r = f[i] - hf.f;
        union { float f; unsigned u; } rr; rr.f = r;
        unsigned ul = rr.u + 0x7FFFu + ((rr.u >> 16) & 1u);
        l[i] = (short)(ul >> 16);
    }
    *hi = (short8_t){ h[0], h[1], h[2], h[3], h[4], h[5], h[6], h[7] };
    *lo = (short8_t){ l[0], l[1], l[2], l[3], l[4], l[5], l[6], l[7] };
}

// ---------------- W precompute: [layer][ncol(128)][k(384)] hi/lo bf16 ----------------

__global__ __launch_bounds__(256) void wprep_kernel(
    const float* __restrict__ W0, const float* __restrict__ Wh, const float* __restrict__ Wl,
    short* __restrict__ Whi_t, short* __restrict__ Wlo_t)
{
    int idx = blockIdx.x * 256 + threadIdx.x;
    const int PER = 128 * 384;
    if (idx >= 7 * PER) return;
    int layer = idx / PER;
    int rem = idx - layer * PER;
    int ncol = rem / 384;
    int k = rem - ncol * 384;
    const float* W; int outc;
    if (layer == 0)      { W = W0; outc = 128; }
    else if (layer < 6)  { W = Wh + (size_t)(layer - 1) * 384 * 128; outc = 128; }
    else                 { W = Wl; outc = 40; }
    float v = (ncol < outc) ? W[(size_t)k * outc + ncol] : 0.f;
    short h, l;
    f2bf_hilo(v, &h, &l);
    Whi_t[idx] = h;
    Wlo_t[idx] = l;
}

// ---------------- feature convert: Z0 = dinv .* X, fp16 ----------------

__global__ __launch_bounds__(256) void fcvt_kernel(const float* __restrict__ in,
                                                   const float* __restrict__ dinv,
                                                   _Float16* __restrict__ out, int total4) {
    int i = blockIdx.x * 256 + threadIdx.x;
    if (i >= total4) return;
    int node = i >> 5;                 // (i*4)/128
    float dv = dinv[node];
    floatx4 v = *(const floatx4*)&in[i * 4];
    half4_t r = { (_Float16)(dv * v.x), (_Float16)(dv * v.y),
                  (_Float16)(dv * v.z), (_Float16)(dv * v.w) };
    *(half4_t*)&out[i * 4] = r;
}

// ---------------- SpMM (Z-space, pure gather-sum) ----------------
// Zout[d] = alpha*dinv2[d]*sum_e Zin[src] + beta*Zo[d]

__global__ __launch_bounds__(256) void spmm_h_kernel(
    _Float16* __restrict__ out, const _Float16* __restrict__ Xin,
    const _Float16* __restrict__ Xo, const float* __restrict__ dinv2,
    const int* __restrict__ rp, const int* __restrict__ cs,
    float alpha, float beta, int n)
{
    int slot = threadIdx.x >> 4;
    int lane = threadIdx.x & 15;
    int node = blockIdx.x * 16 + slot;
    if (node >= n) return;
    const half8_t* X8 = (const half8_t*)Xin;
    float acc[8] = { 0.f, 0.f, 0.f, 0.f, 0.f, 0.f, 0.f, 0.f };
    int s = rp[node], e = rp[node + 1];
    int i = s;
    for (; i + 8 <= e; i += 8) {
        int idx[8];
#pragma unroll
        for (int u = 0; u < 8; ++u) idx[u] = cs[i + u];
        half8_t x[8];
#pragma unroll
        for (int u = 0; u < 8; ++u) x[u] = X8[(size_t)idx[u] * 16 + lane];
#pragma unroll
        for (int u = 0; u < 8; ++u)
#pragma unroll
            for (int j = 0; j < 8; ++j) acc[j] += (float)x[u][j];
    }
    for (; i < e; ++i) {
        int sidx = cs[i];
        half8_t x = X8[(size_t)sidx * 16 + lane];
#pragma unroll
        for (int j = 0; j < 8; ++j) acc[j] += (float)x[j];
    }
    float sc = alpha * dinv2[node];
    half8_t r;
    if (beta != 0.f) {
        half8_t o = ((const half8_t*)Xo)[(size_t)node * 16 + lane];
#pragma unroll
        for (int j = 0; j < 8; ++j) r[j] = (_Float16)(sc * acc[j] + beta * (float)o[j]);
    } else {
#pragma unroll
        for (int j = 0; j < 8; ++j) r[j] = (_Float16)(sc * acc[j]);
    }
    ((half8_t*)out)[(size_t)node * 16 + lane] = r;
}

// ---------------- GEMM: LDS W-slab bf16x3 MFMA, Z-space A ----------------
// A value = sdeg[row] * Z[row][k]; hidden output stored as dinv[row]*relu(..) fp16.

template <int OUTC, int NT, bool HOUT>
__global__ __launch_bounds__(256, 2) void gemm_mfma5_kernel(
    void* __restrict__ outp, const _Float16* __restrict__ X0,
    const _Float16* __restrict__ X1, const _Float16* __restrict__ X2,
    const short* __restrict__ Whi_t, const short* __restrict__ Wlo_t,
    const float* __restrict__ bias, const float* __restrict__ sdeg,
    const float* __restrict__ dinv, int n)
{
    __shared__ short Ws[2][NT * 16][136];

    int tid = threadIdx.x;
    int lane = tid & 63;
    int wave = tid >> 6;
    int m15 = lane & 15;
    int quad = lane >> 4;
    int row0 = blockIdx.x * 128 + wave * 32;

    accfrag acc[2][NT];
#pragma unroll
    for (int mi = 0; mi < 2; ++mi)
#pragma unroll
        for (int nj = 0; nj < NT; ++nj) acc[mi][nj] = (accfrag){0.f, 0.f, 0.f, 0.f};

    int r0 = row0 + m15;
    int r1 = r0 + 16;
    float s0 = (r0 < n) ? sdeg[r0] : 0.f;     // doubles as OOB mask
    float s1 = (r1 < n) ? sdeg[r1] : 0.f;
    size_t ro0 = (size_t)((r0 < n) ? r0 : 0) * 16;   // half8 units
    size_t ro1 = (size_t)((r1 < n) ? r1 : 0) * 16;

    const _Float16* srcs[3] = { X0, X1, X2 };

    for (int sb = 0; sb < 3; ++sb) {
        // stage W slab: NT*16 rows x 128 shorts, hi then lo (contiguous copy)
        {
            const int VEC = NT * 512;
#pragma unroll
            for (int v0 = 0; v0 < VEC; v0 += 256) {
                int v = v0 + tid;
                int a = (v >= NT * 256) ? 1 : 0;
                int rem = v - a * (NT * 256);
                int row = rem >> 4;
                int c8 = (rem & 15) * 8;
                const short* g = (a ? Wlo_t : Whi_t) + (size_t)row * 384 + sb * 128 + c8;
                *(short8_t*)&Ws[a][row][c8] = *(const short8_t*)g;
            }
        }
        __syncthreads();

        const half8_t* Xp8 = (const half8_t*)srcs[sb];
#pragma unroll
        for (int kk = 0; kk < 4; ++kk) {
            int k0 = kk * 32 + quad * 8;
            half8_t h0 = Xp8[ro0 + kk * 4 + quad];
            half8_t h1 = Xp8[ro1 + kk * 4 + quad];
            float f0[8], f1[8];
#pragma unroll
            for (int j = 0; j < 8; ++j) { f0[j] = s0 * (float)h0[j]; f1[j] = s1 * (float)h1[j]; }
            short8_t a_hi[2], a_lo[2];
            split8a(f0, &a_hi[0], &a_lo[0]);
            split8a(f1, &a_hi[1], &a_lo[1]);

#pragma unroll
            for (int nj = 0; nj < NT; ++nj) {
                short8_t b_hi = *(const short8_t*)&Ws[0][nj * 16 + m15][k0];
                short8_t b_lo = *(const short8_t*)&Ws[1][nj * 16 + m15][k0];
#pragma unroll
                for (int mi = 0; mi < 2; ++mi) {
                    acc[mi][nj] = __builtin_amdgcn_mfma_f32_16x16x32_bf16(a_hi[mi], b_hi, acc[mi][nj], 0, 0, 0);
                    acc[mi][nj] = __builtin_amdgcn_mfma_f32_16x16x32_bf16(a_lo[mi], b_hi, acc[mi][nj], 0, 0, 0);
                    acc[mi][nj] = __builtin_amdgcn_mfma_f32_16x16x32_bf16(a_hi[mi], b_lo, acc[mi][nj], 0, 0, 0);
                }
            }
        }
        __syncthreads();
    }

    // epilogue: bias + relu (+ dinv rescale for hidden fp16 store)
    float dvs[2][4];
    if (HOUT) {
#pragma unroll
        for (int mi = 0; mi < 2; ++mi)
#pragma unroll
            for (int reg = 0; reg < 4; ++reg) {
                int gr = row0 + mi * 16 + quad * 4 + reg;
                dvs[mi][reg] = (gr < n) ? dinv[gr] : 0.f;
            }
    }
#pragma unroll
    for (int nj = 0; nj < NT; ++nj) {
        int col = nj * 16 + m15;
        float bv = (col < OUTC) ? bias[col] : 0.f;
#pragma unroll
        for (int mi = 0; mi < 2; ++mi) {
#pragma unroll
            for (int reg = 0; reg < 4; ++reg) {
                int gr = row0 + mi * 16 + quad * 4 + reg;
                if (gr < n && col < OUTC) {
                    float v = acc[mi][nj][reg] + bv;
                    v = v > 0.f ? v : 0.f;
                    if (HOUT) ((_Float16*)outp)[(size_t)gr * OUTC + col] = (_Float16)(v * dvs[mi][reg]);
                    else      ((float*)outp)[(size_t)gr * OUTC + col] = v;
                }
            }
        }
    }
}

// ---------------- launch ----------------

extern "C" void kernel_launch(void* const* d_in, const int* in_sizes, int n_in,
                              void* d_out, int out_size, void* d_ws, size_t ws_size,
                              hipStream_t stream) {
    const float* features = (const float*)d_in[0];
    const int*   src      = (const int*)d_in[1];
    const int*   dst      = (const int*)d_in[2];
    const float* W0       = (const float*)d_in[3];
    const float* b0       = (const float*)d_in[4];
    const float* Wh       = (const float*)d_in[5];
    const float* bh       = (const float*)d_in[6];
    const float* Wl       = (const float*)d_in[7];
    const float* bl       = (const float*)d_in[8];
    float* out = (float*)d_out;

    const int N = NN, E = EE;
    const int WTOT = 7 * 128 * 384;
    const int EB = (E + EPB - 1) / EPB;        // 391 edge blocks
    const int NB2 = (NBK + 255) / 256;         // 7 scan blocks over buckets

    char* ws = (char*)d_ws;
    size_t off = 0;
    auto alloc = [&](size_t bytes) -> void* {
        void* p = ws + off;
        off += (bytes + 511) & ~(size_t)511;
        return p;
    };
    int*      bcnt   = (int*)alloc((size_t)NBK * 4);
    int*      bfill  = (int*)alloc((size_t)NBK * 4);
    int*      bptr   = (int*)alloc((size_t)(NBK + 1) * 4);
    int*      bsum   = (int*)alloc((size_t)NB2 * 4);
    int*      rowptr = (int*)alloc((size_t)(N + 1) * 4);
    int*      ebuf   = (int*)alloc((size_t)E * 4);
    int*      colsrc = (int*)alloc((size_t)E * 4);
    float*    dinv   = (float*)alloc((size_t)N * 4);
    float*    dinv2  = (float*)alloc((size_t)N * 4);
    float*    sdeg   = (float*)alloc((size_t)N * 4);
    short*    Whi_t  = (short*)alloc((size_t)WTOT * 2);
    short*    Wlo_t  = (short*)alloc((size_t)WTOT * 2);
    _Float16* XA     = (_Float16*)alloc((size_t)N * FF * 2);
    _Float16* XB     = (_Float16*)alloc((size_t)N * FF * 2);
    _Float16* B1     = (_Float16*)alloc((size_t)N * FF * 2);
    _Float16* B2     = (_Float16*)alloc((size_t)N * FF * 2);

    // bucketed CSR build
    hipMemsetAsync(bcnt, 0, (size_t)NBK * 4, stream);
    hipMemsetAsync(bfill, 0, (size_t)NBK * 4, stream);
    bhist_kernel<<<EB, 256, 0, stream>>>(dst, bcnt);
    wprep_kernel<<<(WTOT + 255) / 256, 256, 0, stream>>>(W0, Wh, Wl, Whi_t, Wlo_t);
    scan_p1_kernel<<<NB2, 256, 0, stream>>>(bcnt, bsum, NBK);
    scan_p2_kernel<<<1, 1024, 0, stream>>>(bsum, NB2);
    scan_p3_kernel<<<NB2, 256, 0, stream>>>(bcnt, bsum, bptr, NBK);
    bscatter_kernel<<<EB, 256, 0, stream>>>(src, dst, bptr, bfill, ebuf);
    csr_build_kernel<<<NBK, 256, 0, stream>>>(ebuf, bptr, rowptr, colsrc, dinv, dinv2, sdeg);
    fcvt_kernel<<<(N * FF / 4 + 255) / 256, 256, 0, stream>>>(features, dinv, XA, N * FF / 4);

    const _Float16* cur = XA;
    _Float16* nxt = XB;
    int spmm_grid = (N + 15) / 16;
    int gemm_grid = (N + 127) / 128;

    for (int layer = 0; layer < 7; ++layer) {
        const float* b;
        bool last = (layer == 6);
        if (layer == 0)      { b = b0; }
        else if (layer < 6)  { b = bh + (layer - 1) * 128; }
        else                 { b = bl; }
        const short* whl = Whi_t + (size_t)layer * 128 * 384;
        const short* wll = Wlo_t + (size_t)layer * 128 * 384;

        spmm_h_kernel<<<spmm_grid, 256, 0, stream>>>(B1, cur, cur, dinv2, rowptr, colsrc, -1.f, 0.f, N);
        spmm_h_kernel<<<spmm_grid, 256, 0, stream>>>(B2, B1, cur, dinv2, rowptr, colsrc, -2.f, -1.f, N);

        if (!last)
            gemm_mfma5_kernel<128, 8, true><<<gemm_grid, 256, 0, stream>>>(
                (void*)nxt, cur, B1, B2, whl, wll, b, sdeg, dinv, N);
        else
            gemm_mfma5_kernel<40, 3, false><<<gemm_grid, 256, 0, stream>>>(
                (void*)out, cur, B1, B2, whl, wll, b, sdeg, dinv, N);

        if (layer < 6) {
            const _Float16* newcur = nxt;
            nxt = (_Float16*)((nxt == XB) ? XA : XB);
            cur = newcur;
        }
    }
}